// Round 5
// baseline (193.862 us; speedup 1.0000x reference)
//
#include <hip/hip_runtime.h>

#define F 64
#define H 64
#define NT 256
#define TILE_ROWS 256     // per block per iteration: 4 waves x 64 rows
#define ITERS 4
#define ROWS_PER_BLOCK (TILE_ROWS * ITERS)   // 1024
#define WPAD 72   // LDS row stride in bf16 elems (144 B): 2-way bank alias on b64 reads (free)

#define LOG2E 1.44269504088896340736f
#define LN2   0.69314718055994530942f

typedef __bf16 bf16;
typedef __attribute__((ext_vector_type(8))) __bf16 bf16x8;
typedef __attribute__((ext_vector_type(4))) short s16x4;   // v4i16: one 16x16x16 bf16 A/B frag
typedef __attribute__((ext_vector_type(4))) float f32x4;

// LOG2-DOMAIN CELU (R5): activations carry a log2(e) scale end-to-end.
//   y = log2e * x  (x = true pre-activation)
//   z = log2e * celu(x) = med3(y, log2e*exp2(y) - log2e, 0)
// celu(x) = x>0 ? x : exp(x)-1 and expm1(x) >= x for all x, so the median of
// {y, log2e*expm1, 0} picks y when y>0 and log2e*expm1 when y<0. 3 VALU ops
// (v_exp, v_fma, v_med3) vs 5 for mul+exp+sub+cmp+cndmask. Scale bookkeeping:
// w_in,b_in,b_hid pre-scaled by log2e at staging; hidden W UNCHANGED (scale
// passes through: W*(z*ln2)*log2e = W*z); w_out pre-scaled by ln2.
// Robust: y>>0 -> exp2=inf -> med3=y; y<<0 -> exp2=0 -> z=-log2e -> out=-1.
__device__ __forceinline__ float celu_l2(float y) {
    float em = fmaf(LOG2E, __builtin_exp2f(y), -LOG2E);
    return __builtin_amdgcn_fmed3f(y, em, 0.0f);
}

__device__ __forceinline__ short bfb(float v) {
    bf16 h = (bf16)v;
    return __builtin_bit_cast(short, h);
}

// post-layer activation: log2-domain celu on the 4 accum lanes, pack to a v4i16
// bf16 frag. KEY INVARIANT: for v_mfma_f32_16x16x16_bf16 the D layout
// (col=lane&15, row=(lane>>4)*4+j) is IDENTICAL to the B layout, so this frag
// is directly the next layer's B operand (kf = current m). No LDS round-trip.
__device__ __forceinline__ s16x4 celu_frag(f32x4 a) {
    s16x4 r;
    r[0] = bfb(celu_l2(a[0]));
    r[1] = bfb(celu_l2(a[1]));
    r[2] = bfb(celu_l2(a[2]));
    r[3] = bfb(celu_l2(a[3]));
    return r;
}

#define MFMA16(A, B, C) __builtin_amdgcn_mfma_f32_16x16x16bf16_1k((A), (B), (C), 0, 0, 0)
#define SCHED_WALL()    __builtin_amdgcn_sched_barrier(0)

// Block = one feature f x 1024 rows; 4 waves x 64 rows per 256-row tile.
// REGISTER-PRESSURE HISTORY (do not regress):
//   R1 (256,4) 4-n chains    -> SPILL (FETCH 470MB)            274us
//   R2 (256,4) 2-half chains -> SPILL (FETCH 460MB)            248us
//   R3 (256,3) 4-n chains    -> STILL SPILLS (FETCH 254MB)     176us
//   R4 (256,3) + sched_barrier(0) WALLS between layer stages -> NO SPILL
//     (FETCH 35MB, WRITE 64MB), 108.7us, VALU-bound (VALUBusy 85%, Mfma 30%).
//   R5 (this): log2-domain celu (see celu_l2) cuts ~30% of the VALU stream.
// Spill signature to watch: FETCH >> 40MB / WRITE >> 70MB.
__global__ __launch_bounds__(NT, 3) void mlp64(
    const float* __restrict__ x,      // [B,F]
    const float* __restrict__ w_in,
    const float* __restrict__ b_in,
    const float* __restrict__ w_hid,
    const float* __restrict__ b_hid,
    const float* __restrict__ w_out,
    const float* __restrict__ b_out,
    float* __restrict__ out,          // [B,F]
    int Btot)
{
    const int f    = blockIdx.x & (F - 1);
    const int blk  = blockIdx.x >> 6;
    const int row0 = blk * ROWS_PER_BLOCK;
    const int t    = threadIdx.x;
    const int lane = t & 63;
    const int l15  = lane & 15;
    const int q    = lane >> 4;
    const int wrow = (t >> 6) * 64;   // 64-row wave-private slice

    __shared__ __align__(16) bf16  wlds[2][H][WPAD];   // hidden weights [layer][out][in], 18.4 KB
    __shared__ __align__(16) float s_bias[3][H];       // pre-scaled by log2e
    __shared__ __align__(16) float s_wout[H];          // pre-scaled by ln2

    // ---- stage both hidden layers' weights into LDS (fp32 -> bf16, once per block) ----
    for (int idx = t; idx < 1024; idx += NT) {
        const int l   = idx >> 9;
        const int row = (idx >> 3) & 63;
        const int ch  = idx & 7;
        const float* p = w_hid + (((size_t)l * F + f) << 12) + (row << 6) + (ch << 3);
        float4 a = *(const float4*)p, b = *(const float4*)(p + 4);
        bf16x8 v;
        v[0] = (bf16)a.x; v[1] = (bf16)a.y; v[2] = (bf16)a.z; v[3] = (bf16)a.w;
        v[4] = (bf16)b.x; v[5] = (bf16)b.y; v[6] = (bf16)b.z; v[7] = (bf16)b.w;
        *(bf16x8*)&wlds[l][row][ch * 8] = v;
    }
    if (t < H)           s_bias[0][t]         = b_in[f * H + t] * LOG2E;
    else if (t < 2 * H)  s_bias[1][t - H]     = b_hid[(0 * F + f) * H + (t - H)] * LOG2E;
    else if (t < 3 * H)  s_bias[2][t - 2 * H] = b_hid[(1 * F + f) * H + (t - 2 * H)] * LOG2E;
    else                 s_wout[t - 3 * H]    = w_out[f * H + (t - 3 * H)] * LN2;
    __syncthreads();

    // ---- layer-in A frags (log2e-scaled): quad 0 holds (w_hi, w_lo, w_hi, 0) ----
    s16x4 A1[4];
    #pragma unroll
    for (int m = 0; m < 4; ++m) {
        float w  = w_in[f * H + m * 16 + l15] * LOG2E;
        bf16 hb  = (bf16)w;
        short hi = __builtin_bit_cast(short, hb);
        short lo = bfb(w - (float)hb);
        s16x4 v  = {};
        if (q == 0) { v[0] = hi; v[1] = lo; v[2] = hi; }
        A1[m] = v;
    }

    const float bo = b_out[f];

    // strided 4B x loads; sharers are temporally adjacent blocks -> L2 hits
    float xc[4], xn[4];
    #pragma unroll
    for (int n = 0; n < 4; ++n)
        xc[n] = x[(size_t)(row0 + wrow + n * 16 + l15) * F + f];

    #pragma unroll 1
    for (int it = 0; it < ITERS; ++it) {
        const int rbase = row0 + it * TILE_ROWS + wrow;

        // B1 frags: quad 0 holds (x_hi, x_hi, x_lo, 0) in k-slots 0..3
        s16x4 B1[4];
        #pragma unroll
        for (int n = 0; n < 4; ++n) {
            bf16 hb  = (bf16)xc[n];
            short hh = __builtin_bit_cast(short, hb);
            short ll = bfb(xc[n] - (float)hb);
            s16x4 v  = {};
            if (q == 0) { v[0] = hh; v[1] = hh; v[2] = ll; }
            B1[n] = v;
        }
        #pragma unroll
        for (int n = 0; n < 4; ++n)
            xn[n] = (it + 1 < ITERS)
                  ? x[(size_t)(rbase + TILE_ROWS + n * 16 + l15) * F + f] : 0.0f;

        // ---- layer in->H: one K=16 MFMA per (m,n), D-frag -> B-frag of hidden-0 ----
        s16x4 Bh[4][4];                       // [n][kf]
        #pragma unroll
        for (int m = 0; m < 4; ++m) {
            f32x4 c0 = *(const f32x4*)&s_bias[0][m * 16 + q * 4];
            f32x4 a[4];
            #pragma unroll
            for (int n = 0; n < 4; ++n)
                a[n] = MFMA16(A1[m], B1[n], c0);
            #pragma unroll
            for (int n = 0; n < 4; ++n)
                Bh[n][m] = celu_frag(a[n]);
        }

        SCHED_WALL();   // keep hidden-0's ds_reads/live-ranges out of layer-in

        // ---- hidden layer 0 (LDS weight frags, K=16 chain of 4) ----
        s16x4 Bh2[4][4];
        #pragma unroll
        for (int m = 0; m < 4; ++m) {
            s16x4 Aw[4];
            #pragma unroll
            for (int kf = 0; kf < 4; ++kf)
                Aw[kf] = *(const s16x4*)&wlds[0][m * 16 + l15][kf * 16 + q * 4];
            f32x4 c0 = *(const f32x4*)&s_bias[1][m * 16 + q * 4];
            f32x4 a[4];
            #pragma unroll
            for (int n = 0; n < 4; ++n) {
                f32x4 acc = MFMA16(Aw[0], Bh[n][0], c0);
                acc = MFMA16(Aw[1], Bh[n][1], acc);
                acc = MFMA16(Aw[2], Bh[n][2], acc);
                acc = MFMA16(Aw[3], Bh[n][3], acc);
                a[n] = acc;
            }
            #pragma unroll
            for (int n = 0; n < 4; ++n)
                Bh2[n][m] = celu_frag(a[n]);
        }

        SCHED_WALL();   // keep hidden-1's ds_reads/live-ranges out of hidden-0

        // ---- hidden layer 1 + output dot in registers (no cvt on last layer) ----
        {
            float s[4] = {0.0f, 0.0f, 0.0f, 0.0f};
            #pragma unroll
            for (int m = 0; m < 4; ++m) {
                s16x4 Aw[4];
                #pragma unroll
                for (int kf = 0; kf < 4; ++kf)
                    Aw[kf] = *(const s16x4*)&wlds[1][m * 16 + l15][kf * 16 + q * 4];
                f32x4 c0 = *(const f32x4*)&s_bias[2][m * 16 + q * 4];
                f32x4 wo = *(const f32x4*)&s_wout[m * 16 + q * 4];
                f32x4 a[4];
                #pragma unroll
                for (int n = 0; n < 4; ++n) {
                    f32x4 acc = MFMA16(Aw[0], Bh2[n][0], c0);
                    acc = MFMA16(Aw[1], Bh2[n][1], acc);
                    acc = MFMA16(Aw[2], Bh2[n][2], acc);
                    acc = MFMA16(Aw[3], Bh2[n][3], acc);
                    a[n] = acc;
                }
                #pragma unroll
                for (int n = 0; n < 4; ++n)
                    #pragma unroll
                    for (int rr = 0; rr < 4; ++rr)
                        s[n] = fmaf(celu_l2(a[n][rr]), wo[rr], s[n]);
            }
            #pragma unroll
            for (int n = 0; n < 4; ++n) {
                s[n] += __shfl_xor(s[n], 16, 64);
                s[n] += __shfl_xor(s[n], 32, 64);
            }
            if (q == 0) {
                #pragma unroll
                for (int n = 0; n < 4; ++n)
                    out[(size_t)(rbase + n * 16 + l15) * F + f] = s[n] + bo;
            }
        }

        SCHED_WALL();   // keep next iteration's work out of this one's epilogue

        #pragma unroll
        for (int n = 0; n < 4; ++n) xc[n] = xn[n];
    }
}

extern "C" void kernel_launch(void* const* d_in, const int* in_sizes, int n_in,
                              void* d_out, int out_size, void* d_ws, size_t ws_size,
                              hipStream_t stream) {
    const float* x     = (const float*)d_in[0];
    const float* w_in  = (const float*)d_in[1];
    const float* b_in  = (const float*)d_in[2];
    const float* w_hid = (const float*)d_in[3];
    const float* b_hid = (const float*)d_in[4];
    const float* w_out = (const float*)d_in[5];
    const float* b_out = (const float*)d_in[6];
    float* out = (float*)d_out;

    const int Btot = in_sizes[0] / F;                       // 32768
    dim3 grid((unsigned)((Btot / ROWS_PER_BLOCK) * F));     // 2048 blocks
    dim3 block(NT);
    mlp64<<<grid, block, 0, stream>>>(x, w_in, b_in, w_hid, b_hid, w_out, b_out, out, Btot);
}

// Round 6
// 148.213 us; speedup vs baseline: 1.3080x; 1.3080x over previous
//
#include <hip/hip_runtime.h>

#define F 64
#define H 64
#define NT 256
#define TILE_ROWS 256     // per block per iteration: 4 waves x 64 rows
#define ITERS 4
#define ROWS_PER_BLOCK (TILE_ROWS * ITERS)   // 1024
#define WPAD 72   // LDS row stride in bf16 elems (144 B): 2-way bank alias on b64 reads (free)

#define LOG2E 1.44269504088896340736f
#define LN2   0.69314718055994530942f

typedef __bf16 bf16;
typedef __attribute__((ext_vector_type(8))) __bf16 bf16x8;
typedef __attribute__((ext_vector_type(4))) short s16x4;   // v4i16: one 16x16x16 bf16 A/B frag
typedef __attribute__((ext_vector_type(4))) float f32x4;

// LOG2-DOMAIN CELU: activations carry a log2(e) scale end-to-end.
//   y = log2e * x  (x = true pre-activation)
//   z = log2e * celu(x) = med3(y, log2e*exp2(y) - log2e, 0)
// R5 POST-MORTEM: __builtin_exp2f (std exp2) emits a denormal-range fixup
// (cmp+cndmask+exp+mul, ~5 ops) -> VALU cycles +40%, 144us. The RAW instruction
// builtin __builtin_amdgcn_exp2f is bare v_exp_f32: celu = 3 ops total
// (v_exp, v_fma, v_med3) vs 5 for the R4 native-expf path. Raw exp2's flush-
// to-zero for y<-126 is exactly right here: em -> -log2e -> output -1.
// Scale bookkeeping: w_in,b_in,b_hid pre-scaled by log2e at staging; hidden W
// UNCHANGED (scale passes through: W*(z*ln2)*log2e = W*z); w_out by ln2.
__device__ __forceinline__ float celu_l2(float y) {
    float em = fmaf(LOG2E, __builtin_amdgcn_exp2f(y), -LOG2E);
    return __builtin_amdgcn_fmed3f(y, em, 0.0f);
}

__device__ __forceinline__ short bfb(float v) {
    bf16 h = (bf16)v;
    return __builtin_bit_cast(short, h);
}

// post-layer activation: log2-domain celu on the 4 accum lanes, pack to a v4i16
// bf16 frag. KEY INVARIANT: for v_mfma_f32_16x16x16_bf16 the D layout
// (col=lane&15, row=(lane>>4)*4+j) is IDENTICAL to the B layout, so this frag
// is directly the next layer's B operand (kf = current m). No LDS round-trip.
__device__ __forceinline__ s16x4 celu_frag(f32x4 a) {
    s16x4 r;
    r[0] = bfb(celu_l2(a[0]));
    r[1] = bfb(celu_l2(a[1]));
    r[2] = bfb(celu_l2(a[2]));
    r[3] = bfb(celu_l2(a[3]));
    return r;
}

#define MFMA16(A, B, C) __builtin_amdgcn_mfma_f32_16x16x16bf16_1k((A), (B), (C), 0, 0, 0)
#define SCHED_WALL()    __builtin_amdgcn_sched_barrier(0)

// Block = one feature f x 1024 rows; 4 waves x 64 rows per 256-row tile.
// HISTORY (do not regress):
//   R1 (256,4) 4-n chains    -> SPILL (FETCH 470MB)            274us
//   R2 (256,4) 2-half chains -> SPILL (FETCH 460MB)            248us
//   R3 (256,3) 4-n chains    -> STILL SPILLS (FETCH 254MB)     176us
//   R4 (256,3) + sched_barrier(0) WALLS between layer stages -> NO SPILL
//     (FETCH 35MB, WRITE 64MB), 108.7us, VALU-bound (VALUBusy 85%, Mfma 30%).
//   R5 log2-celu via __builtin_exp2f -> denormal-fixup bloat, 144us. REGRESS.
//   R6 (this): same algebra via raw __builtin_amdgcn_exp2f (bare v_exp_f32).
// Spill signature to watch: FETCH >> 40MB / WRITE >> 70MB.
__global__ __launch_bounds__(NT, 3) void mlp64(
    const float* __restrict__ x,      // [B,F]
    const float* __restrict__ w_in,
    const float* __restrict__ b_in,
    const float* __restrict__ w_hid,
    const float* __restrict__ b_hid,
    const float* __restrict__ w_out,
    const float* __restrict__ b_out,
    float* __restrict__ out,          // [B,F]
    int Btot)
{
    const int f    = blockIdx.x & (F - 1);
    const int blk  = blockIdx.x >> 6;
    const int row0 = blk * ROWS_PER_BLOCK;
    const int t    = threadIdx.x;
    const int lane = t & 63;
    const int l15  = lane & 15;
    const int q    = lane >> 4;
    const int wrow = (t >> 6) * 64;   // 64-row wave-private slice

    __shared__ __align__(16) bf16  wlds[2][H][WPAD];   // hidden weights [layer][out][in], 18.4 KB
    __shared__ __align__(16) float s_bias[3][H];       // pre-scaled by log2e
    __shared__ __align__(16) float s_wout[H];          // pre-scaled by ln2

    // ---- stage both hidden layers' weights into LDS (fp32 -> bf16, once per block) ----
    for (int idx = t; idx < 1024; idx += NT) {
        const int l   = idx >> 9;
        const int row = (idx >> 3) & 63;
        const int ch  = idx & 7;
        const float* p = w_hid + (((size_t)l * F + f) << 12) + (row << 6) + (ch << 3);
        float4 a = *(const float4*)p, b = *(const float4*)(p + 4);
        bf16x8 v;
        v[0] = (bf16)a.x; v[1] = (bf16)a.y; v[2] = (bf16)a.z; v[3] = (bf16)a.w;
        v[4] = (bf16)b.x; v[5] = (bf16)b.y; v[6] = (bf16)b.z; v[7] = (bf16)b.w;
        *(bf16x8*)&wlds[l][row][ch * 8] = v;
    }
    if (t < H)           s_bias[0][t]         = b_in[f * H + t] * LOG2E;
    else if (t < 2 * H)  s_bias[1][t - H]     = b_hid[(0 * F + f) * H + (t - H)] * LOG2E;
    else if (t < 3 * H)  s_bias[2][t - 2 * H] = b_hid[(1 * F + f) * H + (t - 2 * H)] * LOG2E;
    else                 s_wout[t - 3 * H]    = w_out[f * H + (t - 3 * H)] * LN2;
    __syncthreads();

    // ---- layer-in A frags (log2e-scaled): quad 0 holds (w_hi, w_lo, w_hi, 0) ----
    s16x4 A1[4];
    #pragma unroll
    for (int m = 0; m < 4; ++m) {
        float w  = w_in[f * H + m * 16 + l15] * LOG2E;
        bf16 hb  = (bf16)w;
        short hi = __builtin_bit_cast(short, hb);
        short lo = bfb(w - (float)hb);
        s16x4 v  = {};
        if (q == 0) { v[0] = hi; v[1] = lo; v[2] = hi; }
        A1[m] = v;
    }

    const float bo = b_out[f];

    // strided 4B x loads; sharers are temporally adjacent blocks -> L2 hits
    float xc[4], xn[4];
    #pragma unroll
    for (int n = 0; n < 4; ++n)
        xc[n] = x[(size_t)(row0 + wrow + n * 16 + l15) * F + f];

    #pragma unroll 1
    for (int it = 0; it < ITERS; ++it) {
        const int rbase = row0 + it * TILE_ROWS + wrow;

        // B1 frags: quad 0 holds (x_hi, x_hi, x_lo, 0) in k-slots 0..3
        s16x4 B1[4];
        #pragma unroll
        for (int n = 0; n < 4; ++n) {
            bf16 hb  = (bf16)xc[n];
            short hh = __builtin_bit_cast(short, hb);
            short ll = bfb(xc[n] - (float)hb);
            s16x4 v  = {};
            if (q == 0) { v[0] = hh; v[1] = hh; v[2] = ll; }
            B1[n] = v;
        }
        #pragma unroll
        for (int n = 0; n < 4; ++n)
            xn[n] = (it + 1 < ITERS)
                  ? x[(size_t)(rbase + TILE_ROWS + n * 16 + l15) * F + f] : 0.0f;

        // ---- layer in->H: one K=16 MFMA per (m,n), D-frag -> B-frag of hidden-0 ----
        s16x4 Bh[4][4];                       // [n][kf]
        #pragma unroll
        for (int m = 0; m < 4; ++m) {
            f32x4 c0 = *(const f32x4*)&s_bias[0][m * 16 + q * 4];
            f32x4 a[4];
            #pragma unroll
            for (int n = 0; n < 4; ++n)
                a[n] = MFMA16(A1[m], B1[n], c0);
            #pragma unroll
            for (int n = 0; n < 4; ++n)
                Bh[n][m] = celu_frag(a[n]);
        }

        SCHED_WALL();   // keep hidden-0's ds_reads/live-ranges out of layer-in

        // ---- hidden layer 0 (LDS weight frags, K=16 chain of 4) ----
        s16x4 Bh2[4][4];
        #pragma unroll
        for (int m = 0; m < 4; ++m) {
            s16x4 Aw[4];
            #pragma unroll
            for (int kf = 0; kf < 4; ++kf)
                Aw[kf] = *(const s16x4*)&wlds[0][m * 16 + l15][kf * 16 + q * 4];
            f32x4 c0 = *(const f32x4*)&s_bias[1][m * 16 + q * 4];
            f32x4 a[4];
            #pragma unroll
            for (int n = 0; n < 4; ++n) {
                f32x4 acc = MFMA16(Aw[0], Bh[n][0], c0);
                acc = MFMA16(Aw[1], Bh[n][1], acc);
                acc = MFMA16(Aw[2], Bh[n][2], acc);
                acc = MFMA16(Aw[3], Bh[n][3], acc);
                a[n] = acc;
            }
            #pragma unroll
            for (int n = 0; n < 4; ++n)
                Bh2[n][m] = celu_frag(a[n]);
        }

        SCHED_WALL();   // keep hidden-1's ds_reads/live-ranges out of hidden-0

        // ---- hidden layer 1 + output dot in registers (no cvt on last layer) ----
        {
            float s[4] = {0.0f, 0.0f, 0.0f, 0.0f};
            #pragma unroll
            for (int m = 0; m < 4; ++m) {
                s16x4 Aw[4];
                #pragma unroll
                for (int kf = 0; kf < 4; ++kf)
                    Aw[kf] = *(const s16x4*)&wlds[1][m * 16 + l15][kf * 16 + q * 4];
                f32x4 c0 = *(const f32x4*)&s_bias[2][m * 16 + q * 4];
                f32x4 wo = *(const f32x4*)&s_wout[m * 16 + q * 4];
                f32x4 a[4];
                #pragma unroll
                for (int n = 0; n < 4; ++n) {
                    f32x4 acc = MFMA16(Aw[0], Bh2[n][0], c0);
                    acc = MFMA16(Aw[1], Bh2[n][1], acc);
                    acc = MFMA16(Aw[2], Bh2[n][2], acc);
                    acc = MFMA16(Aw[3], Bh2[n][3], acc);
                    a[n] = acc;
                }
                #pragma unroll
                for (int n = 0; n < 4; ++n)
                    #pragma unroll
                    for (int rr = 0; rr < 4; ++rr)
                        s[n] = fmaf(celu_l2(a[n][rr]), wo[rr], s[n]);
            }
            #pragma unroll
            for (int n = 0; n < 4; ++n) {
                s[n] += __shfl_xor(s[n], 16, 64);
                s[n] += __shfl_xor(s[n], 32, 64);
            }
            if (q == 0) {
                #pragma unroll
                for (int n = 0; n < 4; ++n)
                    out[(size_t)(rbase + n * 16 + l15) * F + f] = s[n] + bo;
            }
        }

        SCHED_WALL();   // keep next iteration's work out of this one's epilogue

        #pragma unroll
        for (int n = 0; n < 4; ++n) xc[n] = xn[n];
    }
}

extern "C" void kernel_launch(void* const* d_in, const int* in_sizes, int n_in,
                              void* d_out, int out_size, void* d_ws, size_t ws_size,
                              hipStream_t stream) {
    const float* x     = (const float*)d_in[0];
    const float* w_in  = (const float*)d_in[1];
    const float* b_in  = (const float*)d_in[2];
    const float* w_hid = (const float*)d_in[3];
    const float* b_hid = (const float*)d_in[4];
    const float* w_out = (const float*)d_in[5];
    const float* b_out = (const float*)d_in[6];
    float* out = (float*)d_out;

    const int Btot = in_sizes[0] / F;                       // 32768
    dim3 grid((unsigned)((Btot / ROWS_PER_BLOCK) * F));     // 2048 blocks
    dim3 block(NT);
    mlp64<<<grid, block, 0, stream>>>(x, w_in, b_in, w_hid, b_hid, w_out, b_out, out, Btot);
}